// Round 1
// 265.212 us; speedup vs baseline: 1.0181x; 1.0181x over previous
//
#include <hip/hip_runtime.h>
#include <cstdint>
#include <cstddef>

#define BB 128
#define NN 512
#define EE 512
#define KK 256
#define STR 17  // odd stride: column reads across 64 lanes are 2-way/bank = free

__device__ __forceinline__ float wave_reduce_max(float v) {
#pragma unroll
  for (int off = 32; off >= 1; off >>= 1) v = fmaxf(v, __shfl_xor(v, off, 64));
  return v;
}
__device__ __forceinline__ float wave_reduce_sum(float v) {
#pragma unroll
  for (int off = 32; off >= 1; off >>= 1) v += __shfl_xor(v, off, 64);
  return v;
}

// ---- DPP cross-lane reduces (VALU pipe, not LDS). row_shr 1/2/4/8 then
// row_bcast15/31 accumulates the wave64 total into lane 63 (rocPRIM pattern).
template <int CTRL>
__device__ __forceinline__ float dppz(float x) {  // invalid/off lanes contribute 0
  return __int_as_float(__builtin_amdgcn_update_dpp(0, __float_as_int(x), CTRL, 0xf, 0xf, false));
}
template <int CTRL>
__device__ __forceinline__ float dppi(float x) {  // invalid/off lanes contribute x (identity)
  return __int_as_float(__builtin_amdgcn_update_dpp(__float_as_int(x), __float_as_int(x), CTRL, 0xf, 0xf, false));
}
__device__ __forceinline__ float wave_sum64(float x) {  // -> uniform (sgpr)
  x += dppz<0x111>(x); x += dppz<0x112>(x); x += dppz<0x114>(x); x += dppz<0x118>(x);
  x += dppz<0x142>(x); x += dppz<0x143>(x);
  return __int_as_float(__builtin_amdgcn_readlane(__float_as_int(x), 63));
}
__device__ __forceinline__ float wave_max64nn(float x) {  // nonneg inputs
  x = fmaxf(x, dppz<0x111>(x)); x = fmaxf(x, dppz<0x112>(x));
  x = fmaxf(x, dppz<0x114>(x)); x = fmaxf(x, dppz<0x118>(x));
  x = fmaxf(x, dppz<0x142>(x)); x = fmaxf(x, dppz<0x143>(x));
  return __int_as_float(__builtin_amdgcn_readlane(__float_as_int(x), 63));
}
__device__ __forceinline__ float wave_min64(float x) {
  x = fminf(x, dppi<0x111>(x)); x = fminf(x, dppi<0x112>(x));
  x = fminf(x, dppi<0x114>(x)); x = fminf(x, dppi<0x118>(x));
  x = fminf(x, dppi<0x142>(x)); x = fminf(x, dppi<0x143>(x));
  return __int_as_float(__builtin_amdgcn_readlane(__float_as_int(x), 63));
}

// Lower median (rank 127) of 256 nonnegative values, 4 per lane. Exact.
// Guided bisection: pivot0 = 0.845*mean (half-normal median/mean ratio),
// then a fixed-density Newton step, then bracket secant; accepts cnt==128
// (answer = max of <pivot set) or cnt==127 (answer = min of >=pivot set).
// Bracket starts at [0, S] (S = sum >= max), so every exit is exact.
__device__ __forceinline__ float wave_median256_fast(float a0, float a1, float a2, float a3) {
  float S = wave_sum64((a0 + a1) + (a2 + a3));
  float mean = S * 0.00390625f;
  float lo = 0.f, hi = S * 1.0000002f + 1e-37f;  // cnt(hi)=256 always
  int c_lo = 0, c_hi = 256;
  float piv = 0.845f * mean;
  float ans = 0.f;
  bool have = false;
#pragma unroll 1
  for (int it = 0; it < 34; ++it) {
    if (!(piv > lo && piv < hi)) piv = 0.5f * (lo + hi);
    int cnt = __popcll(__ballot(a0 < piv)) + __popcll(__ballot(a1 < piv)) +
              __popcll(__ballot(a2 < piv)) + __popcll(__ballot(a3 < piv));
    if (cnt == 128) {
      float m = fmaxf(fmaxf(a0 < piv ? a0 : 0.f, a1 < piv ? a1 : 0.f),
                      fmaxf(a2 < piv ? a2 : 0.f, a3 < piv ? a3 : 0.f));
      ans = wave_max64nn(m); have = true; break;
    }
    if (cnt == 127) {
      float m = fminf(fminf(a0 >= piv ? a0 : 3.4e38f, a1 >= piv ? a1 : 3.4e38f),
                      fminf(a2 >= piv ? a2 : 3.4e38f, a3 >= piv ? a3 : 3.4e38f));
      ans = wave_min64(m); have = true; break;
    }
    if (cnt < 127) { lo = piv; c_lo = cnt; } else { hi = piv; c_hi = cnt; }
    if (it == 0) piv = piv + (127.5f - (float)cnt) * mean * 0.0077f;  // Newton, density 130/mean
    else piv = lo + (hi - lo) * ((127.5f - (float)c_lo) / (float)(c_hi - c_lo));
    if (it >= 10) piv = 0.5f * (lo + hi);  // guarantee geometric convergence
  }
  if (!have) {  // tie-collapsed bracket: ranks 126..128 all == lo; max{a<hi} exact
    float m = fmaxf(fmaxf(a0 < hi ? a0 : 0.f, a1 < hi ? a1 : 0.f),
                    fmaxf(a2 < hi ? a2 : 0.f, a3 < hi ? a3 : 0.f));
    ans = wave_max64nn(m);
  }
  return ans;
}

// Fused stage: per block (b,g) covering 16 columns — stage the 512x16 errs
// tile in LDS once, 32 chunk-medians (4 per wave, 8 waves), exp relaxation
// scalars, head-term partial, partial dots epart[e] = sum_{n in grp} errs*lam.
// 512 threads: LDS still 35 KB -> 4 blocks/CU = 32 waves/CU (was 16), and the
// serial median chain per wave halves (8->4).
__global__ __launch_bounds__(512, 8) void kfused(
    const float* __restrict__ head, const float* __restrict__ errs,
    float* __restrict__ ws_delta, float* __restrict__ ws_htpart,
    float* __restrict__ ws_epart) {
  __shared__ float tile[512 * STR];  // 34816 B -> 4 blocks/CU
  __shared__ float medbuf[32];       // [chunk*16 + col]
  __shared__ float lambuf[16];
  __shared__ float redm[8];
  const int blk = blockIdx.x;
  const int b = blk >> 5, g = blk & 31;
  const int n0 = g * 16;
  const int tid = threadIdx.x, wave = tid >> 6, lane = tid & 63;

  // per-row head max (2 KB read, L2-hit for 31/32 blocks)
  float m = head[(size_t)b * NN + tid];
  m = wave_reduce_max(m);
  if (lane == 0) redm[wave] = m;

  // stage 512 rows x 16 cols (row segment = 64 B contiguous per 4 lanes)
  const int tr = tid >> 2, tc = (tid & 3) * 4;
  const float* src = errs + (size_t)b * EE * NN + n0 + tc;
#pragma unroll
  for (int i = 0; i < 4; ++i) {
    int row = i * 128 + tr;
    float4 v = *(const float4*)(src + (size_t)row * NN);
    float* dst = &tile[row * STR + tc];
    dst[0] = v.x; dst[1] = v.y; dst[2] = v.z; dst[3] = v.w;
  }
  __syncthreads();

  // 32 medians: pair p = wave*4+j (chunk = p>>4, col = p&15)
#pragma unroll 1
  for (int j = 0; j < 4; ++j) {
    int p = wave * 4 + j;
    int col = p & 15;
    int rb = (p >> 4) * 256;
    float a0 = fabsf(tile[(rb + lane) * STR + col]);
    float a1 = fabsf(tile[(rb + lane + 64) * STR + col]);
    float a2 = fabsf(tile[(rb + lane + 128) * STR + col]);
    float a3 = fabsf(tile[(rb + lane + 192) * STR + col]);
    float med = wave_median256_fast(a0, a1, a2, a3);
    if (lane == 0) medbuf[p] = med;
  }
  __syncthreads();

  // exp relaxation scalars for the 16 columns
  float htp = 0.f;
  if (tid < 16) {
    float hmax = fmaxf(fmaxf(fmaxf(redm[0], redm[1]), fmaxf(redm[2], redm[3])),
                       fmaxf(fmaxf(redm[4], redm[5]), fmaxf(redm[6], redm[7])));
    int n = n0 + tid;
    float l1 = medbuf[tid] + medbuf[16 + tid];
    float th = head[(size_t)b * NN + n] - hmax;
    float lb = th - l1, ub = th + l1;
    float lam, mu, delta;
    if (ub == lb) {
      lam = 0.f; mu = expf(ub); delta = 0.f;
    } else {
      float elb = expf(lb), eub = expf(ub);
      float lam_s = (eub - elb) / (ub - lb + 1e-6f);
      lam = fminf(lam_s, expf(lb + 0.9f));
      float ub0 = (lam > lam_s) ? (elb - lam * lb) : (eub - lam * ub);
      float t = lam * (1.f - logf(lam));
      mu = 0.5f * (t + ub0);
      delta = 0.5f * (ub0 - t);
    }
    lambuf[tid] = lam;
    ws_delta[(size_t)b * NN + n] = delta;
    htp = th * lam + mu;
  }
  if (wave == 0) {
    float s = wave_reduce_sum(htp);  // lanes 16..63 contribute 0
    if (lane == 0) ws_htpart[b * 32 + g] = s;
  }
  __syncthreads();

  // partial dots from the LDS tile (one row per thread)
  float s0 = 0.f;
#pragma unroll
  for (int j = 0; j < 16; ++j) s0 = fmaf(tile[tid * STR + j], lambuf[j], s0);
  ws_epart[((size_t)(b * 32 + g)) * 512 + tid] = s0;
}

// cexp part of exp_errs: full dot cauchy_exp[b,j,:] . delta[b,:].
// 2048 blocks (4x more TLP), 4 rows per wave with 4 independent DPP reduce
// chains (ILP). delta re-reads are L2-hits (256 KB resident).
__global__ __launch_bounds__(256) void kcexp(
    const float* __restrict__ cexp, const float* __restrict__ ws_delta,
    float* __restrict__ ws_ee2) {
  const int blk = blockIdx.x;  // 2048 blocks
  const int b = blk >> 4, seg = blk & 15;
  const int wave = threadIdx.x >> 6, lane = threadIdx.x & 63;
  const float* wsrc = ws_delta + (size_t)b * NN;
  float4 wa = *(const float4*)(wsrc + 4 * lane);
  float4 wb = *(const float4*)(wsrc + 256 + 4 * lane);
  const int r0 = seg * 16 + wave * 4;
  const float* base = cexp + (size_t)b * KK * NN;
  float* out = ws_ee2 + (size_t)b * KK;
  float s0, s1, s2, s3;
  {
    const float* rp = base + (size_t)r0 * NN;
    float4 x = *(const float4*)(rp + 4 * lane);
    float4 y = *(const float4*)(rp + 256 + 4 * lane);
    s0 = x.x * wa.x + x.y * wa.y + x.z * wa.z + x.w * wa.w +
         y.x * wb.x + y.y * wb.y + y.z * wb.z + y.w * wb.w;
  }
  {
    const float* rp = base + (size_t)(r0 + 1) * NN;
    float4 x = *(const float4*)(rp + 4 * lane);
    float4 y = *(const float4*)(rp + 256 + 4 * lane);
    s1 = x.x * wa.x + x.y * wa.y + x.z * wa.z + x.w * wa.w +
         y.x * wb.x + y.y * wb.y + y.z * wb.z + y.w * wb.w;
  }
  {
    const float* rp = base + (size_t)(r0 + 2) * NN;
    float4 x = *(const float4*)(rp + 4 * lane);
    float4 y = *(const float4*)(rp + 256 + 4 * lane);
    s2 = x.x * wa.x + x.y * wa.y + x.z * wa.z + x.w * wa.w +
         y.x * wb.x + y.y * wb.y + y.z * wb.z + y.w * wb.w;
  }
  {
    const float* rp = base + (size_t)(r0 + 3) * NN;
    float4 x = *(const float4*)(rp + 4 * lane);
    float4 y = *(const float4*)(rp + 256 + 4 * lane);
    s3 = x.x * wa.x + x.y * wa.y + x.z * wa.z + x.w * wa.w +
         y.x * wb.x + y.y * wb.y + y.z * wb.z + y.w * wb.w;
  }
  s0 = wave_sum64(s0);
  s1 = wave_sum64(s1);
  s2 = wave_sum64(s2);
  s3 = wave_sum64(s3);
  if (lane == 0) {
    out[r0] = s0; out[r0 + 1] = s1; out[r0 + 2] = s2; out[r0 + 3] = s3;
  }
}

// Reduce the 32 per-group partials into exp_errs[0:512] per b.
// 256 blocks, fully coalesced (consecutive threads -> consecutive e).
__global__ __launch_bounds__(256) void kreduce(
    const float* __restrict__ ws_epart, float* __restrict__ ws_ee1) {
  const int idx = blockIdx.x * 256 + threadIdx.x;  // 65536 = 128*512
  const int b = idx >> 9, e = idx & 511;
  const float* pp = ws_epart + (size_t)b * 32 * 512 + e;
  float acc = 0.f;
#pragma unroll
  for (int g = 0; g < 32; ++g) acc += pp[g * 512];
  ws_ee1[idx] = acc;
}

// Stage 3: per b — load pre-reduced exp_errs, append cexp dots, exp_head sum
// from htparts, 3 medians of 256, log relaxation, outputs.
__global__ __launch_bounds__(256) void kstage3(
    const float* __restrict__ head, const float* __restrict__ clog,
    const float* __restrict__ ws_htpart, const float* __restrict__ ws_ee1,
    const float* __restrict__ ws_ee2, float* __restrict__ out) {
  __shared__ float eb[768];
  __shared__ float redm[4];
  __shared__ float meds[3];
  __shared__ float sc[2];
  __shared__ float ehsh;
  const int b = blockIdx.x;
  const int tid = threadIdx.x, wave = tid >> 6, lane = tid & 63;

  float m = fmaxf(head[(size_t)b * NN + tid], head[(size_t)b * NN + 256 + tid]);
  m = wave_reduce_max(m);
  if (lane == 0) redm[wave] = m;

  eb[tid] = ws_ee1[(size_t)b * NN + tid];
  eb[tid + 256] = ws_ee1[(size_t)b * NN + 256 + tid];
  eb[tid + 512] = ws_ee2[(size_t)b * KK + tid];
  __syncthreads();

  if (wave < 3) {
    const float* p = eb + wave * 256;
    float a0 = fabsf(p[lane]), a1 = fabsf(p[lane + 64]);
    float a2 = fabsf(p[lane + 128]), a3 = fabsf(p[lane + 192]);
    float med = wave_median256_fast(a0, a1, a2, a3);
    if (lane == 0) meds[wave] = med;
  } else {
    float v = (lane < 32) ? ws_htpart[b * 32 + lane] : 0.f;
    v = wave_reduce_sum(v);
    if (lane == 0) ehsh = v;
  }
  __syncthreads();

  if (tid == 0) {
    float hmax = fmaxf(fmaxf(redm[0], redm[1]), fmaxf(redm[2], redm[3]));
    float eh = ehsh;
    float l1 = meds[0] + meds[1] + meds[2];
    float lb = eh - l1, ub = eh + l1;
    float lam, mu, delta;
    if (ub == lb) {
      lam = 0.f; mu = logf(ub); delta = 0.f;
    } else {
      float llb = logf(lb + 1e-6f);
      float lam_s = (logf(ub) - llb) / (ub - lb + 1e-6f);
      lam = lam_s;
      float lb0 = llb - lb * lam;  // reference's where(lam<lam_s,...) always takes else
      float t = -logf(lam) - 1.f;
      mu = 0.5f * (t + lb0);
      delta = 0.5f * (t - lb0);
    }
    sc[0] = lam; sc[1] = delta;
    out[b] = eh * lam + mu + hmax;
  }
  __syncthreads();
  float lam = sc[0], delta = sc[1];
  float* ob = out + BB + (size_t)b * 1024;
  ob[tid] = eb[tid] * lam;
  ob[tid + 256] = eb[tid + 256] * lam;
  ob[tid + 512] = eb[tid + 512] * lam;
  ob[tid + 768] = delta * clog[(size_t)b * KK + tid];
}

extern "C" void kernel_launch(void* const* d_in, const int* in_sizes, int n_in,
                              void* d_out, int out_size, void* d_ws, size_t ws_size,
                              hipStream_t stream) {
  const float* head = (const float*)d_in[0];   // (128, 512)
  const float* errs = (const float*)d_in[1];   // (65536, 512)
  const float* cexp = (const float*)d_in[2];   // (128, 256, 512)
  const float* clog = (const float*)d_in[3];   // (128, 256)
  float* out = (float*)d_out;                  // 128 + 131072 floats

  float* ws = (float*)d_ws;
  float* ws_delta = ws;                        // 65536
  float* ws_htpart = ws_delta + BB * NN;       // 4096
  float* ws_ee2 = ws_htpart + BB * 32;         // 32768
  float* ws_ee1 = ws_ee2 + BB * KK;            // 65536
  float* ws_epart = ws_ee1 + BB * NN;          // 128*32*512 = 2097152

  hipLaunchKernelGGL(kfused, dim3(BB * 32), dim3(512), 0, stream,
                     head, errs, ws_delta, ws_htpart, ws_epart);
  hipLaunchKernelGGL(kcexp, dim3(BB * 16), dim3(256), 0, stream,
                     cexp, ws_delta, ws_ee2);
  hipLaunchKernelGGL(kreduce, dim3(256), dim3(256), 0, stream,
                     ws_epart, ws_ee1);
  hipLaunchKernelGGL(kstage3, dim3(BB), dim3(256), 0, stream,
                     head, clog, ws_htpart, ws_ee1, ws_ee2, out);
}